// Round 1
// 291.537 us; speedup vs baseline: 1.0107x; 1.0107x over previous
//
#include <hip/hip_runtime.h>
#include <hip/hip_bf16.h>
#include <stdint.h>

#define B_SZ 4
#define SEQ 2048
#define DM 1024
#define NH 16
#define DK 64
#define BH (B_SZ * NH)      // 64
#define M_TOT (B_SZ * SEQ)  // 8192

typedef unsigned short u16;
typedef u16 u16x8 __attribute__((ext_vector_type(8)));
typedef __bf16 bf16x8 __attribute__((ext_vector_type(8)));
typedef float f32x4 __attribute__((ext_vector_type(4)));

__device__ __forceinline__ u16 f2bf(float f) {
    union { float f; uint32_t u; } v; v.f = f;
    uint32_t u = v.u;
    return (u16)((u + 0x7FFFu + ((u >> 16) & 1u)) >> 16);
}

// truncating fp32->bf16 (1 op; used only for P in [0,1])
__device__ __forceinline__ u16 f2bf_trunc(float f) {
    union { float f; uint32_t u; } v; v.f = f;
    return (u16)(v.u >> 16);
}

__device__ __forceinline__ f32x4 mfma16(u16x8 a, u16x8 b, f32x4 c) {
    return __builtin_amdgcn_mfma_f32_16x16x32_bf16(
        __builtin_bit_cast(bf16x8, a), __builtin_bit_cast(bf16x8, b), c, 0, 0, 0);
}

// async global->LDS, 16 B per lane; lds dest = wave-uniform base + lane*16
__device__ __forceinline__ void gload16_lds(const void* g, void* l) {
    __builtin_amdgcn_global_load_lds(
        (const __attribute__((address_space(1))) void*)(uintptr_t)g,
        (__attribute__((address_space(3))) void*)(uintptr_t)l, 16, 0, 0);
}

// ---------------- x fp32 -> bf16 ----------------
__global__ void cvt_bf16_kernel(const float* __restrict__ in, u16* __restrict__ out, int n4) {
    int i = blockIdx.x * blockDim.x + threadIdx.x;
    if (i < n4) {
        float4 v = ((const float4*)in)[i];
        ushort4 o;
        o.x = f2bf(v.x); o.y = f2bf(v.y); o.z = f2bf(v.z); o.w = f2bf(v.w);
        ((ushort4*)out)[i] = o;
    }
}

// ---------------- W [K][N] fp32 -> Wt [N][K] bf16 (z = weight index) ----------------
__global__ void transpose_w_kernel(const float* __restrict__ W0, const float* __restrict__ W1,
                                   u16* __restrict__ Wt) {
    __shared__ u16 tile[32][33];
    int bx = blockIdx.x, by = blockIdx.y, z = blockIdx.z;
    const float* W = z ? W1 : W0;
    u16* Wd = Wt + (size_t)z * DM * DM;
    int t = threadIdx.x;
    for (int i = 0; i < 4; i++) {
        int idx = t + i * 256;
        int r = idx >> 5, c = idx & 31;
        tile[r][c] = f2bf(W[(by * 32 + r) * DM + bx * 32 + c]);
    }
    __syncthreads();
    for (int i = 0; i < 4; i++) {
        int idx = t + i * 256;
        int r2 = idx >> 5, c2 = idx & 31;
        Wd[(bx * 32 + r2) * DM + by * 32 + c2] = tile[c2][r2];
    }
}

// ---------------- 128x128x32 bf16 GEMM, global_load_lds staging ----------------
// MODE 0: bf16 scatter to [bh][s][dk]; n<1024 -> C0 (scaled by scale0), else C1.
// MODE 1: fp32 row-major [M][1024] -> C0.
// MODE 2: bf16 TRANSPOSED scatter to Vt[bh][d][s] -> C0 (fused V transpose).
template <int AFP32, int MODE>
__global__ __launch_bounds__(256, 2) void gemm128(
    const void* __restrict__ Ain, const u16* __restrict__ Bt,
    void* __restrict__ C0p, void* __restrict__ C1p, float scale0) {
    __shared__ u16 As[128][32];
    __shared__ u16 Bs[128][32];
    const int K = DM;
    int m0 = blockIdx.x * 128;
    int n0 = blockIdx.y * 128;
    int tid = threadIdx.x;
    int lane = tid & 63, wave = tid >> 6;
    int quad = lane >> 4, l15 = lane & 15;
    int wm = wave >> 1, wn = wave & 1;

    f32x4 acc[4][4];
    for (int i = 0; i < 4; i++)
        for (int j = 0; j < 4; j++) acc[i][j] = f32x4{0.f, 0.f, 0.f, 0.f};

    int rS = lane >> 2;
    int cS = (lane & 3) * 8;

    for (int k0 = 0; k0 < K; k0 += 32) {
        __syncthreads();
        if (AFP32) {
            const float* A = (const float*)Ain;
            for (int i = 0; i < 4; i++) {
                int idx = tid + i * 256;
                int r = idx >> 3, c = (idx & 7) * 4;
                float4 v = *(const float4*)(&A[(size_t)(m0 + r) * K + k0 + c]);
                ushort4 o;
                o.x = f2bf(v.x); o.y = f2bf(v.y); o.z = f2bf(v.z); o.w = f2bf(v.w);
                *(ushort4*)(&As[r][c]) = o;
            }
        } else {
            const u16* A = (const u16*)Ain;
            const u16* ga = &A[(size_t)(m0 + wave * 32 + rS) * K + k0 + cS];
            gload16_lds(ga, &As[wave * 32][0]);
            gload16_lds(ga + (size_t)16 * K, &As[wave * 32 + 16][0]);
        }
        {
            const u16* gb = &Bt[(size_t)(n0 + wave * 32 + rS) * K + k0 + cS];
            gload16_lds(gb, &Bs[wave * 32][0]);
            gload16_lds(gb + (size_t)16 * K, &Bs[wave * 32 + 16][0]);
        }
        __syncthreads();
        u16x8 af[4], bfv[4];
        for (int mt = 0; mt < 4; mt++)
            af[mt] = *(const u16x8*)(&As[wm * 64 + mt * 16 + l15][quad * 8]);
        for (int nt = 0; nt < 4; nt++)
            bfv[nt] = *(const u16x8*)(&Bs[wn * 64 + nt * 16 + l15][quad * 8]);
        for (int mt = 0; mt < 4; mt++)
            for (int nt = 0; nt < 4; nt++)
                acc[mt][nt] = mfma16(af[mt], bfv[nt], acc[mt][nt]);
    }

    for (int mt = 0; mt < 4; mt++)
        for (int nt = 0; nt < 4; nt++)
            for (int r = 0; r < 4; r++) {
                int m = m0 + wm * 64 + mt * 16 + quad * 4 + r;
                int n = n0 + wn * 64 + nt * 16 + l15;
                float v = acc[mt][nt][r];
                if (MODE == 0) {
                    v *= (n < 1024) ? scale0 : 1.0f;
                    u16* C = (n < 1024) ? (u16*)C0p : (u16*)C1p;
                    int ne = n & 1023;
                    int b = m >> 11, s = m & 2047;
                    int h = ne >> 6, d = ne & 63;
                    C[(((size_t)(b * NH + h) * SEQ) + s) * DK + d] = f2bf(v);
                } else if (MODE == 1) {
                    ((float*)C0p)[(size_t)m * DM + n] = v;
                } else {  // MODE 2: Vt[bh][d][s]
                    int b = m >> 11, s = m & 2047;
                    int h = n >> 6, d = n & 63;
                    ((u16*)C0p)[(((size_t)(b * NH + h) * DK) + d) * SEQ + s] = f2bf(v);
                }
            }
}

// ---------------- causal flash attention v6 ----------------
// Q pre-scaled by (1/8)*log2(e). K: [bh][s][64]. Vt: [bh][d][s]. Out: [b*SEQ+s][h*64+d] bf16.
// Grid (bh, 32): qs = 31 - blockIdx.y (longest-first); XCD = bh%8 preserved.
// Block = 4 waves x 16 q-rows. 2048 blocks; LDS 41.5 KB -> 3 blocks/CU = 12 waves/CU.
// v6 changes vs v5:
//  - K/V tiles merged to [64][64] (128B rows) with 16B-granule XOR swizzle
//    (granule ^= row&7). global_load_lds writes linearly, so the SOURCE address
//    is pre-swizzled (same involution) and reads apply the swizzle -> the
//    ds_read_b128 B-fragment reads are bank-conflict-free (was 8-way).
//  - 2-phase pipeline: double-buffered K/V, next tile's 8 global_load_lds
//    issued before current tile's compute; single __syncthreads per iteration
//    (its vmcnt(0) drain is now covered by ~600 cycles of MFMA/VALU).
__global__ __launch_bounds__(256, 3) void attn_kernel(
    const u16* __restrict__ Qb, const u16* __restrict__ Kb,
    const u16* __restrict__ Vtb, u16* __restrict__ AOb) {
    __shared__ u16 Kl[2][64][64];   // [buf][key][d], swizzled granules
    __shared__ u16 Vl[2][64][64];   // [buf][d][key], swizzled granules
    __shared__ u16 Pl[64][68];      // P scratch; stride 68 -> conflict-free

    int bh = blockIdx.x;            // 0..63
    int qs = 31 - blockIdx.y;       // longest blocks first
    int q0 = qs * 64;
    int tid = threadIdx.x, lane = tid & 63, wave = tid >> 6;  // wave 0..3
    int quad = lane >> 4, l15 = lane & 15;
    int b = bh >> 4, h = bh & 15;

    const u16* Qg = Qb + (size_t)bh * SEQ * DK;
    const u16* Kg = Kb + (size_t)bh * SEQ * DK;
    const u16* Vg = Vtb + (size_t)bh * DK * SEQ;

    int rw = lane >> 3;             // 0..7: row-within-8 for staging
    int gsw = (lane & 7) ^ rw;      // pre-swizzled source 16B-granule
    int sw8 = l15 & 15 & 7;         // row&7 for fragment reads (row = nt*16+l15)
    u16* Pw = &Pl[wave * 16][0];

    // Q fragments: global -> regs; wave owns rows [16w,16w+16)
    u16x8 aq[2];
    for (int kc = 0; kc < 2; kc++)
        aq[kc] = *(const u16x8*)(
            &Qg[(size_t)(q0 + wave * 16 + l15) * DK + kc * 32 + quad * 8]);

    float lsum[4];
    f32x4 O[4];
    for (int r = 0; r < 4; r++) lsum[r] = 0.f;
    for (int nt = 0; nt < 4; nt++) O[nt] = f32x4{0.f, 0.f, 0.f, 0.f};

    // prologue: stage tile 0 into buf 0
    {
        const u16* gk = &Kg[(size_t)(wave * 16 + rw) * DK + gsw * 8];
        gload16_lds(gk, &Kl[0][wave * 16][0]);
        gload16_lds(gk + 8 * DK, &Kl[0][wave * 16 + 8][0]);
        const u16* gv = &Vg[(size_t)(wave * 16 + rw) * SEQ + gsw * 8];
        gload16_lds(gv, &Vl[0][wave * 16][0]);
        gload16_lds(gv + 8 * SEQ, &Vl[0][wave * 16 + 8][0]);
    }
    __syncthreads();

    int buf = 0;
    for (int kt = 0; kt <= qs; kt++) {
        // issue next tile's loads into buf^1; they stay in flight across compute
        if (kt < qs) {
            int k0n = (kt + 1) * 64;
            const u16* gk = &Kg[(size_t)(k0n + wave * 16 + rw) * DK + gsw * 8];
            gload16_lds(gk, &Kl[buf ^ 1][wave * 16][0]);
            gload16_lds(gk + 8 * DK, &Kl[buf ^ 1][wave * 16 + 8][0]);
            const u16* gv = &Vg[(size_t)(wave * 16 + rw) * SEQ + k0n + gsw * 8];
            gload16_lds(gv, &Vl[buf ^ 1][wave * 16][0]);
            gload16_lds(gv + 8 * SEQ, &Vl[buf ^ 1][wave * 16 + 8][0]);
        }

        // S = Q K^T : 8 MFMA (16x64 out tile); swizzled conflict-free reads
        f32x4 sc[4];
        for (int nt = 0; nt < 4; nt++) {
            const u16* kr = &Kl[buf][nt * 16 + l15][0];
            u16x8 b0 = *(const u16x8*)(kr + (quad ^ sw8) * 8);
            u16x8 b1 = *(const u16x8*)(kr + ((4 + quad) ^ sw8) * 8);
            f32x4 z = f32x4{0.f, 0.f, 0.f, 0.f};
            z = mfma16(aq[0], b0, z);
            z = mfma16(aq[1], b1, z);
            sc[nt] = z;
        }
        // P = exp2(S); causal mask only on diagonal tile (wave-uniform branch)
        if (kt == qs) {
            for (int nt = 0; nt < 4; nt++)
                for (int r = 0; r < 4; r++) {
                    int qq = wave * 16 + quad * 4 + r;
                    int kk = nt * 16 + l15;
                    float e = exp2f(sc[nt][r]);
                    float pv = (kk <= qq) ? e : 0.f;
                    sc[nt][r] = pv;
                    lsum[r] += pv;
                }
        } else {
            for (int nt = 0; nt < 4; nt++)
                for (int r = 0; r < 4; r++) {
                    float pv = exp2f(sc[nt][r]);
                    sc[nt][r] = pv;
                    lsum[r] += pv;
                }
        }
        // P -> wave-private LDS slice (C-layout -> row-major); truncating cvt
        for (int nt = 0; nt < 4; nt++)
            for (int r = 0; r < 4; r++)
                Pw[(size_t)(quad * 4 + r) * 68 + nt * 16 + l15] = f2bf_trunc(sc[nt][r]);
        // O += P V : 8 MFMA
        u16x8 ap0 = *(const u16x8*)(&Pw[(size_t)l15 * 68 + quad * 8]);
        u16x8 ap1 = *(const u16x8*)(&Pw[(size_t)l15 * 68 + 32 + quad * 8]);
        for (int nt = 0; nt < 4; nt++) {
            const u16* vr = &Vl[buf][nt * 16 + l15][0];
            u16x8 b0 = *(const u16x8*)(vr + (quad ^ sw8) * 8);
            u16x8 b1 = *(const u16x8*)(vr + ((4 + quad) ^ sw8) * 8);
            O[nt] = mfma16(ap0, b0, O[nt]);
            O[nt] = mfma16(ap1, b1, O[nt]);
        }
        __syncthreads();  // drains vmcnt (next tile staged) + all buf reads done
        buf ^= 1;
    }

    // epilogue: reduce lsum across the 16 column lanes, normalize, store
    for (int r = 0; r < 4; r++) {
        float s = lsum[r];
        for (int off = 1; off < 16; off <<= 1) s += __shfl_xor(s, off, 64);
        float inv = 1.0f / s;
        int q = q0 + wave * 16 + quad * 4 + r;
        for (int nt = 0; nt < 4; nt++) {
            int d = nt * 16 + l15;
            AOb[((size_t)(b * SEQ + q)) * DM + h * DK + d] = f2bf(O[nt][r] * inv);
        }
    }
}

extern "C" void kernel_launch(void* const* d_in, const int* in_sizes, int n_in,
                              void* d_out, int out_size, void* d_ws, size_t ws_size,
                              hipStream_t stream) {
    const float* x = (const float*)d_in[0];
    const float* Wq = (const float*)d_in[1];
    const float* Wk = (const float*)d_in[2];
    const float* Wv = (const float*)d_in[3];
    const float* Wo = (const float*)d_in[4];
    float* out = (float*)d_out;

    // Regions: ws = S0|S1 (16 MB each), d_out = D0|D1 (16 MB each).
    // 1. cvt x -> xb@S0
    // 2. T(Wq,Wk) -> wqk@D0 head (4 MB)
    // 3. gemmQK(xb, wqk) -> Q@S1 (scaled), K@D1
    // 4. T(Wv) -> wvt@S0 head (xb dead: V-GEMM reads fp32 x directly)
    // 5. gemmV MODE2 (x fp32, wvt) -> Vt@D0 [bh][d][s] (overwrites wqk head)
    // 6. attn(Q@S1, K@D1, Vt@D0) -> AO@S0 (over dead wvt/xb)
    // 7. T(Wo) -> wot@S1 head (Q dead)
    // 8. gemmO(AO@S0, wot@S1h) -> d_out fp32 (D0+D1; Vt,K dead)
    const size_t HALF = (size_t)M_TOT * DM * 2;  // 16 MB
    char* S0 = (char*)d_ws;
    char* S1 = (char*)d_ws + HALF;
    char* D0 = (char*)d_out;
    char* D1 = (char*)d_out + HALF;

    u16* xb  = (u16*)S0;
    u16* Qb  = (u16*)S1;
    u16* Kb  = (u16*)D1;
    u16* Vt  = (u16*)D0;
    u16* AOb = (u16*)S0;
    u16* wqk = (u16*)D0;   // 4 MB
    u16* wvt = (u16*)S0;   // 2 MB over dead xb
    u16* wot = (u16*)S1;   // 2 MB over dead Q

    const float cscale = 0.125f * 1.44269504088896f;  // 1/sqrt(64) * log2(e)
    dim3 tg2(32, 32, 2);
    dim3 tg1(32, 32, 1);
    dim3 gg(M_TOT / 128, DM / 128);

    // 1) x -> bf16
    int n4 = M_TOT * DM / 4;
    cvt_bf16_kernel<<<n4 / 256, 256, 0, stream>>>(x, xb, n4);

    // 2-3) fused Q,K projection (Q pre-scaled)
    transpose_w_kernel<<<tg2, 256, 0, stream>>>(Wq, Wk, wqk);
    dim3 gqk(M_TOT / 128, 2048 / 128);
    gemm128<0, 0><<<gqk, 256, 0, stream>>>(xb, wqk, (void*)Qb, (void*)Kb, cscale);

    // 4-5) V projection with fused transpose (fp32 A from d_in)
    transpose_w_kernel<<<tg1, 256, 0, stream>>>(Wv, Wv, wvt);
    gemm128<1, 2><<<gg, 256, 0, stream>>>(x, wvt, (void*)Vt, (void*)Vt, 1.0f);

    // 6) attention
    dim3 ag(BH, 32);
    attn_kernel<<<ag, 256, 0, stream>>>(Qb, Kb, Vt, AOb);

    // 7-8) output projection straight into d_out
    transpose_w_kernel<<<tg1, 256, 0, stream>>>(Wo, Wo, wot);
    gemm128<0, 1><<<gg, 256, 0, stream>>>(AOb, wot, (void*)out, (void*)out, 1.0f);
}

// Round 2
// 266.895 us; speedup vs baseline: 1.1040x; 1.0923x over previous
//
#include <hip/hip_runtime.h>
#include <hip/hip_bf16.h>
#include <stdint.h>

#define B_SZ 4
#define SEQ 2048
#define DM 1024
#define NH 16
#define DK 64
#define BH (B_SZ * NH)      // 64
#define M_TOT (B_SZ * SEQ)  // 8192

typedef unsigned short u16;
typedef u16 u16x8 __attribute__((ext_vector_type(8)));
typedef __bf16 bf16x8 __attribute__((ext_vector_type(8)));
typedef float f32x4 __attribute__((ext_vector_type(4)));

__device__ __forceinline__ u16 f2bf(float f) {
    union { float f; uint32_t u; } v; v.f = f;
    uint32_t u = v.u;
    return (u16)((u + 0x7FFFu + ((u >> 16) & 1u)) >> 16);
}

// truncating fp32->bf16 (1 op; used only for P in [0,1])
__device__ __forceinline__ u16 f2bf_trunc(float f) {
    union { float f; uint32_t u; } v; v.f = f;
    return (u16)(v.u >> 16);
}

__device__ __forceinline__ f32x4 mfma16(u16x8 a, u16x8 b, f32x4 c) {
    return __builtin_amdgcn_mfma_f32_16x16x32_bf16(
        __builtin_bit_cast(bf16x8, a), __builtin_bit_cast(bf16x8, b), c, 0, 0, 0);
}

// async global->LDS, 16 B per lane; lds dest = wave-uniform base + lane*16
__device__ __forceinline__ void gload16_lds(const void* g, void* l) {
    __builtin_amdgcn_global_load_lds(
        (const __attribute__((address_space(1))) void*)(uintptr_t)g,
        (__attribute__((address_space(3))) void*)(uintptr_t)l, 16, 0, 0);
}

// ---------------- x fp32 -> bf16 ----------------
__global__ void cvt_bf16_kernel(const float* __restrict__ in, u16* __restrict__ out, int n4) {
    int i = blockIdx.x * blockDim.x + threadIdx.x;
    if (i < n4) {
        float4 v = ((const float4*)in)[i];
        ushort4 o;
        o.x = f2bf(v.x); o.y = f2bf(v.y); o.z = f2bf(v.z); o.w = f2bf(v.w);
        ((ushort4*)out)[i] = o;
    }
}

// ---------------- W [K][N] fp32 -> Wt [N][K] bf16 (z = weight index) ----------------
__global__ void transpose_w_kernel(const float* __restrict__ W0, const float* __restrict__ W1,
                                   u16* __restrict__ Wt) {
    __shared__ u16 tile[32][33];
    int bx = blockIdx.x, by = blockIdx.y, z = blockIdx.z;
    const float* W = z ? W1 : W0;
    u16* Wd = Wt + (size_t)z * DM * DM;
    int t = threadIdx.x;
    for (int i = 0; i < 4; i++) {
        int idx = t + i * 256;
        int r = idx >> 5, c = idx & 31;
        tile[r][c] = f2bf(W[(by * 32 + r) * DM + bx * 32 + c]);
    }
    __syncthreads();
    for (int i = 0; i < 4; i++) {
        int idx = t + i * 256;
        int r2 = idx >> 5, c2 = idx & 31;
        Wd[(bx * 32 + r2) * DM + by * 32 + c2] = tile[c2][r2];
    }
}

// ---------------- 128x128x32 bf16 GEMM, global_load_lds staging ----------------
// MODE 0: bf16 scatter to [bh][s][dk]; n<1024 -> C0 (scaled by scale0), else C1.
// MODE 1: fp32 row-major [M][1024] -> C0.
// MODE 2: bf16 TRANSPOSED scatter to Vt[bh][d][s] -> C0 (fused V transpose).
template <int AFP32, int MODE>
__global__ __launch_bounds__(256, 2) void gemm128(
    const void* __restrict__ Ain, const u16* __restrict__ Bt,
    void* __restrict__ C0p, void* __restrict__ C1p, float scale0) {
    __shared__ u16 As[128][32];
    __shared__ u16 Bs[128][32];
    const int K = DM;
    int m0 = blockIdx.x * 128;
    int n0 = blockIdx.y * 128;
    int tid = threadIdx.x;
    int lane = tid & 63, wave = tid >> 6;
    int quad = lane >> 4, l15 = lane & 15;
    int wm = wave >> 1, wn = wave & 1;

    f32x4 acc[4][4];
    for (int i = 0; i < 4; i++)
        for (int j = 0; j < 4; j++) acc[i][j] = f32x4{0.f, 0.f, 0.f, 0.f};

    int rS = lane >> 2;
    int cS = (lane & 3) * 8;

    for (int k0 = 0; k0 < K; k0 += 32) {
        __syncthreads();
        if (AFP32) {
            const float* A = (const float*)Ain;
            for (int i = 0; i < 4; i++) {
                int idx = tid + i * 256;
                int r = idx >> 3, c = (idx & 7) * 4;
                float4 v = *(const float4*)(&A[(size_t)(m0 + r) * K + k0 + c]);
                ushort4 o;
                o.x = f2bf(v.x); o.y = f2bf(v.y); o.z = f2bf(v.z); o.w = f2bf(v.w);
                *(ushort4*)(&As[r][c]) = o;
            }
        } else {
            const u16* A = (const u16*)Ain;
            const u16* ga = &A[(size_t)(m0 + wave * 32 + rS) * K + k0 + cS];
            gload16_lds(ga, &As[wave * 32][0]);
            gload16_lds(ga + (size_t)16 * K, &As[wave * 32 + 16][0]);
        }
        {
            const u16* gb = &Bt[(size_t)(n0 + wave * 32 + rS) * K + k0 + cS];
            gload16_lds(gb, &Bs[wave * 32][0]);
            gload16_lds(gb + (size_t)16 * K, &Bs[wave * 32 + 16][0]);
        }
        __syncthreads();
        u16x8 af[4], bfv[4];
        for (int mt = 0; mt < 4; mt++)
            af[mt] = *(const u16x8*)(&As[wm * 64 + mt * 16 + l15][quad * 8]);
        for (int nt = 0; nt < 4; nt++)
            bfv[nt] = *(const u16x8*)(&Bs[wn * 64 + nt * 16 + l15][quad * 8]);
        for (int mt = 0; mt < 4; mt++)
            for (int nt = 0; nt < 4; nt++)
                acc[mt][nt] = mfma16(af[mt], bfv[nt], acc[mt][nt]);
    }

    for (int mt = 0; mt < 4; mt++)
        for (int nt = 0; nt < 4; nt++)
            for (int r = 0; r < 4; r++) {
                int m = m0 + wm * 64 + mt * 16 + quad * 4 + r;
                int n = n0 + wn * 64 + nt * 16 + l15;
                float v = acc[mt][nt][r];
                if (MODE == 0) {
                    v *= (n < 1024) ? scale0 : 1.0f;
                    u16* C = (n < 1024) ? (u16*)C0p : (u16*)C1p;
                    int ne = n & 1023;
                    int b = m >> 11, s = m & 2047;
                    int h = ne >> 6, d = ne & 63;
                    C[(((size_t)(b * NH + h) * SEQ) + s) * DK + d] = f2bf(v);
                } else if (MODE == 1) {
                    ((float*)C0p)[(size_t)m * DM + n] = v;
                } else {  // MODE 2: Vt[bh][d][s]
                    int b = m >> 11, s = m & 2047;
                    int h = n >> 6, d = n & 63;
                    ((u16*)C0p)[(((size_t)(b * NH + h) * DK) + d) * SEQ + s] = f2bf(v);
                }
            }
}

// ---------------- causal flash attention v7 ----------------
// Q pre-scaled by (1/8)*log2(e). K: [bh][s][64]. Vt: [bh][d][s]. Out: [b*SEQ+s][h*64+d] bf16.
// Grid (bh, 16): qs = 15 - blockIdx.y (longest-first); XCD = bh%8 preserved.
// Block = 4 waves x 32 q-rows = 128 q-rows; KV tile 64 keys, double-buffered+swizzled.
// v7 vs v6: 2x q-tile per block -> half the barriers per unit work, two independent
// q-group dependency chains per wave per iteration (softmax of g0 overlaps QK^T of g1),
// 16-MFMA clusters wrapped in s_setprio (T5). P scratch now [4][32][64] XOR-swizzled
// (same granule involution as K/V; stores/reads max 2-way = free).
// LDS 48 KB -> 3 blocks/CU. Waves 0-1 skip the final (fully-masked) key tile.
__global__ __launch_bounds__(256, 3) void attn_kernel(
    const u16* __restrict__ Qb, const u16* __restrict__ Kb,
    const u16* __restrict__ Vtb, u16* __restrict__ AOb) {
    __shared__ u16 Kl[2][64][64];   // [buf][key][d], swizzled 16B granules
    __shared__ u16 Vl[2][64][64];   // [buf][d][key], swizzled 16B granules
    __shared__ u16 Pl[4][32][64];   // [wave][qrow][key], swizzled 16B granules

    int bh = blockIdx.x;            // 0..63
    int qs = 15 - blockIdx.y;       // longest blocks first
    int q0 = qs * 128;
    int tid = threadIdx.x, lane = tid & 63, wave = tid >> 6;  // wave 0..3
    int quad = lane >> 4, l15 = lane & 15;
    int b = bh >> 4, h = bh & 15;

    const u16* Qg = Qb + (size_t)bh * SEQ * DK;
    const u16* Kg = Kb + (size_t)bh * SEQ * DK;
    const u16* Vg = Vtb + (size_t)bh * DK * SEQ;

    int rw = lane >> 3;             // 0..7: row-within-8 for staging
    int gsw = (lane & 7) ^ rw;      // pre-swizzled source 16B-granule
    int sw8 = l15 & 7;              // row&7 for fragment reads
    u16* Pw = &Pl[wave][0][0];

    // Q fragments: global -> regs; wave owns q rows [32w, 32w+32), 2 groups of 16
    u16x8 aq[2][2];
    for (int g = 0; g < 2; g++)
        for (int kc = 0; kc < 2; kc++)
            aq[g][kc] = *(const u16x8*)(
                &Qg[(size_t)(q0 + wave * 32 + g * 16 + l15) * DK + kc * 32 + quad * 8]);

    float lsum[2][4];
    f32x4 O[2][4];
    for (int g = 0; g < 2; g++)
        for (int r = 0; r < 4; r++) lsum[g][r] = 0.f;
    for (int g = 0; g < 2; g++)
        for (int nt = 0; nt < 4; nt++) O[g][nt] = f32x4{0.f, 0.f, 0.f, 0.f};

    // prologue: stage tile 0 into buf 0
    {
        const u16* gk = &Kg[(size_t)(wave * 16 + rw) * DK + gsw * 8];
        gload16_lds(gk, &Kl[0][wave * 16][0]);
        gload16_lds(gk + 8 * DK, &Kl[0][wave * 16 + 8][0]);
        const u16* gv = &Vg[(size_t)(wave * 16 + rw) * SEQ + gsw * 8];
        gload16_lds(gv, &Vl[0][wave * 16][0]);
        gload16_lds(gv + 8 * SEQ, &Vl[0][wave * 16 + 8][0]);
    }
    __syncthreads();

    int nkt = 2 * qs + 2;                 // key tiles for this q block
    int lastkt = 2 * qs + (wave >> 1);    // this wave's diagonal tile
    int buf = 0;
    for (int kt = 0; kt < nkt; kt++) {
        // issue next tile's loads into buf^1; in flight across compute
        if (kt + 1 < nkt) {
            int k0n = (kt + 1) * 64;
            const u16* gk = &Kg[(size_t)(k0n + wave * 16 + rw) * DK + gsw * 8];
            gload16_lds(gk, &Kl[buf ^ 1][wave * 16][0]);
            gload16_lds(gk + 8 * DK, &Kl[buf ^ 1][wave * 16 + 8][0]);
            const u16* gv = &Vg[(size_t)(wave * 16 + rw) * SEQ + k0n + gsw * 8];
            gload16_lds(gv, &Vl[buf ^ 1][wave * 16][0]);
            gload16_lds(gv + 8 * SEQ, &Vl[buf ^ 1][wave * 16 + 8][0]);
        }

        if (kt <= lastkt) {   // wave-uniform; waves 0-1 skip their fully-masked last tile
            bool diag = (kt == lastkt);
            // S = Q K^T : 16 MFMA (two 16x64 tiles), swizzled conflict-free reads
            f32x4 sc[2][4];
            __builtin_amdgcn_s_setprio(1);
            #pragma unroll
            for (int nt = 0; nt < 4; nt++) {
                const u16* kr = &Kl[buf][nt * 16 + l15][0];
                u16x8 b0 = *(const u16x8*)(kr + (quad ^ sw8) * 8);
                u16x8 b1 = *(const u16x8*)(kr + ((4 + quad) ^ sw8) * 8);
                #pragma unroll
                for (int g = 0; g < 2; g++) {
                    f32x4 z = f32x4{0.f, 0.f, 0.f, 0.f};
                    z = mfma16(aq[g][0], b0, z);
                    z = mfma16(aq[g][1], b1, z);
                    sc[g][nt] = z;
                }
            }
            __builtin_amdgcn_s_setprio(0);
            // P = exp2(S); causal mask only on the wave's diagonal tile
            #pragma unroll
            for (int g = 0; g < 2; g++) {
                if (diag) {
                    #pragma unroll
                    for (int nt = 0; nt < 4; nt++)
                        #pragma unroll
                        for (int r = 0; r < 4; r++) {
                            int qq = q0 + wave * 32 + g * 16 + quad * 4 + r;
                            int kk = kt * 64 + nt * 16 + l15;
                            float e = exp2f(sc[g][nt][r]);
                            float pv = (kk <= qq) ? e : 0.f;
                            sc[g][nt][r] = pv;
                            lsum[g][r] += pv;
                        }
                } else {
                    #pragma unroll
                    for (int nt = 0; nt < 4; nt++)
                        #pragma unroll
                        for (int r = 0; r < 4; r++) {
                            float pv = exp2f(sc[g][nt][r]);
                            sc[g][nt][r] = pv;
                            lsum[g][r] += pv;
                        }
                }
                // P -> wave-private swizzled LDS slice; truncating cvt
                #pragma unroll
                for (int nt = 0; nt < 4; nt++)
                    #pragma unroll
                    for (int r = 0; r < 4; r++) {
                        int prow = g * 16 + quad * 4 + r;
                        int pcol = nt * 16 + l15;
                        int scol = (((pcol >> 3) ^ (prow & 7)) << 3) | (pcol & 7);
                        Pw[prow * 64 + scol] = f2bf_trunc(sc[g][nt][r]);
                    }
            }
            // O += P V : 16 MFMA
            u16x8 ap[2][2];
            #pragma unroll
            for (int g = 0; g < 2; g++)
                #pragma unroll
                for (int kc = 0; kc < 2; kc++)
                    ap[g][kc] = *(const u16x8*)(
                        &Pw[(g * 16 + l15) * 64 + (((kc * 4 + quad) ^ sw8) << 3)]);
            __builtin_amdgcn_s_setprio(1);
            #pragma unroll
            for (int nt = 0; nt < 4; nt++) {
                const u16* vr = &Vl[buf][nt * 16 + l15][0];
                u16x8 b0 = *(const u16x8*)(vr + (quad ^ sw8) * 8);
                u16x8 b1 = *(const u16x8*)(vr + ((4 + quad) ^ sw8) * 8);
                #pragma unroll
                for (int g = 0; g < 2; g++) {
                    O[g][nt] = mfma16(ap[g][0], b0, O[g][nt]);
                    O[g][nt] = mfma16(ap[g][1], b1, O[g][nt]);
                }
            }
            __builtin_amdgcn_s_setprio(0);
        }
        __syncthreads();  // drains vmcnt (next tile staged) + all buf reads done
        buf ^= 1;
    }

    // epilogue: reduce lsum across the 16 column lanes, normalize, store
    #pragma unroll
    for (int g = 0; g < 2; g++)
        #pragma unroll
        for (int r = 0; r < 4; r++) {
            float s = lsum[g][r];
            for (int off = 1; off < 16; off <<= 1) s += __shfl_xor(s, off, 64);
            float inv = 1.0f / s;
            int q = q0 + wave * 32 + g * 16 + quad * 4 + r;
            #pragma unroll
            for (int nt = 0; nt < 4; nt++) {
                int d = nt * 16 + l15;
                AOb[((size_t)(b * SEQ + q)) * DM + h * DK + d] = f2bf(O[g][nt][r] * inv);
            }
        }
}

extern "C" void kernel_launch(void* const* d_in, const int* in_sizes, int n_in,
                              void* d_out, int out_size, void* d_ws, size_t ws_size,
                              hipStream_t stream) {
    const float* x = (const float*)d_in[0];
    const float* Wq = (const float*)d_in[1];
    const float* Wk = (const float*)d_in[2];
    const float* Wv = (const float*)d_in[3];
    const float* Wo = (const float*)d_in[4];
    float* out = (float*)d_out;

    // Regions: ws = S0|S1 (16 MB each), d_out = D0|D1 (16 MB each).
    // 1. cvt x -> xb@S0
    // 2. T(Wq,Wk) -> wqk@D0 head (4 MB)
    // 3. gemmQK(xb, wqk) -> Q@S1 (scaled), K@D1
    // 4. T(Wv) -> wvt@S0 head (xb dead: V-GEMM reads fp32 x directly)
    // 5. gemmV MODE2 (x fp32, wvt) -> Vt@D0 [bh][d][s] (overwrites wqk head)
    // 6. attn(Q@S1, K@D1, Vt@D0) -> AO@S0 (over dead wvt/xb)
    // 7. T(Wo) -> wot@S1 head (Q dead)
    // 8. gemmO(AO@S0, wot@S1h) -> d_out fp32 (D0+D1; Vt,K dead)
    const size_t HALF = (size_t)M_TOT * DM * 2;  // 16 MB
    char* S0 = (char*)d_ws;
    char* S1 = (char*)d_ws + HALF;
    char* D0 = (char*)d_out;
    char* D1 = (char*)d_out + HALF;

    u16* xb  = (u16*)S0;
    u16* Qb  = (u16*)S1;
    u16* Kb  = (u16*)D1;
    u16* Vt  = (u16*)D0;
    u16* AOb = (u16*)S0;
    u16* wqk = (u16*)D0;   // 4 MB
    u16* wvt = (u16*)S0;   // 2 MB over dead xb
    u16* wot = (u16*)S1;   // 2 MB over dead Q

    const float cscale = 0.125f * 1.44269504088896f;  // 1/sqrt(64) * log2(e)
    dim3 tg2(32, 32, 2);
    dim3 tg1(32, 32, 1);
    dim3 gg(M_TOT / 128, DM / 128);

    // 1) x -> bf16
    int n4 = M_TOT * DM / 4;
    cvt_bf16_kernel<<<n4 / 256, 256, 0, stream>>>(x, xb, n4);

    // 2-3) fused Q,K projection (Q pre-scaled)
    transpose_w_kernel<<<tg2, 256, 0, stream>>>(Wq, Wk, wqk);
    dim3 gqk(M_TOT / 128, 2048 / 128);
    gemm128<0, 0><<<gqk, 256, 0, stream>>>(xb, wqk, (void*)Qb, (void*)Kb, cscale);

    // 4-5) V projection with fused transpose (fp32 A from d_in)
    transpose_w_kernel<<<tg1, 256, 0, stream>>>(Wv, Wv, wvt);
    gemm128<1, 2><<<gg, 256, 0, stream>>>(x, wvt, (void*)Vt, (void*)Vt, 1.0f);

    // 6) attention
    dim3 ag(BH, 16);
    attn_kernel<<<ag, 256, 0, stream>>>(Qb, Kb, Vt, AOb);

    // 7-8) output projection straight into d_out
    transpose_w_kernel<<<tg1, 256, 0, stream>>>(Wo, Wo, wot);
    gemm128<0, 1><<<gg, 256, 0, stream>>>(AOb, wot, (void*)out, (void*)out, 1.0f);
}